// Round 3
// baseline (274.197 us; speedup 1.0000x reference)
//
#include <hip/hip_runtime.h>
#include <hip/hip_bf16.h>

#define GENES 20000
#define DD    128
#define PP    32
#define HH    128
#define NB    4096
#define GOUT  20000
#define GPAD  20096   // GOUT padded to multiple of 128
#define CPB   16      // combos per encoder block

typedef __attribute__((ext_vector_type(8))) short bf16x8;
typedef __attribute__((ext_vector_type(4))) float f32x4;

__device__ __forceinline__ unsigned short f2bf(float f) {
    unsigned int u = __float_as_uint(f);
    unsigned int lsb = (u >> 16) & 1u;
    u += 0x7fffu + lsb;                      // RTNE
    return (unsigned short)(u >> 16);
}
__device__ __forceinline__ unsigned int f2bf2(float a, float b) {
    return (unsigned int)f2bf(a) | ((unsigned int)f2bf(b) << 16);
}

// raw barrier: drain LDS ops only — global prefetch loads stay in flight
#define BARRIER() do { \
    asm volatile("s_waitcnt lgkmcnt(0)" ::: "memory"); \
    __builtin_amdgcn_s_barrier(); \
    asm volatile("" ::: "memory"); \
} while (0)

// XOR-swizzled ushort offset inside a [rows][128] bf16 tile (16B-chunk swizzle).
__device__ __forceinline__ int swz(int r, int c) {
    return r * 128 + (((c >> 3) ^ (r & 15)) << 3) + (c & 7);
}

// ---------------- K0a: W1,W2 -> plain transposed bf16 (row-major [h][d]) -----
__global__ void prep_weights(const float* __restrict__ W1, const float* __restrict__ W2,
                             unsigned short* __restrict__ w1t, unsigned short* __restrict__ w2t) {
    int o = blockIdx.x * 512 + threadIdx.x;
#pragma unroll
    for (int k = 0; k < 2; ++k, o += 256) {
        int h = o >> 7, d = o & 127;
        w1t[o] = f2bf(W1[d * 128 + h]);   // W1T[h][d] = W1[d][h]
        w2t[o] = f2bf(W2[d * 128 + h]);
    }
}

// ---------------- K0b: Wout [128][20000] f32 -> WoutT [20096][128] bf16 -------
__global__ void prep_wout(const float* __restrict__ Wout, unsigned short* __restrict__ woutT) {
    int g = blockIdx.x * 256 + threadIdx.x;
    if (g >= GPAD) return;
    if (g < GOUT) {
        for (int d0 = 0; d0 < 128; d0 += 8) {
            unsigned short buf[8];
#pragma unroll
            for (int j = 0; j < 8; ++j) buf[j] = f2bf(Wout[(size_t)(d0 + j) * GOUT + g]);
            *reinterpret_cast<uint4*>(&woutT[(size_t)g * 128 + d0]) =
                *reinterpret_cast<const uint4*>(buf);
        }
    } else {
        uint4 z = {0u, 0u, 0u, 0u};
        for (int d0 = 0; d0 < 128; d0 += 8)
            *reinterpret_cast<uint4*>(&woutT[(size_t)g * 128 + d0]) = z;
    }
}

// ---------------- K1: encoder, weights-in-registers, raw barriers ------------
__global__ __launch_bounds__(512, 2) void encoder_kernel(
    const float* __restrict__ gene, const float* __restrict__ b1g,
    const float* __restrict__ b2g, const float* __restrict__ pwg,
    const int* __restrict__ locs_gene, const int* __restrict__ locs_combos,
    const unsigned short* __restrict__ w1t, const unsigned short* __restrict__ w2t,
    unsigned short* __restrict__ poolbf)
{
    __shared__ __align__(16) unsigned short aBuf[2][64 * 128];  // 2 x 16 KB swizzled
    __shared__ float pcol[2][4][64];
    __shared__ float wrow[64];
    __shared__ float pp[8][128];

    const int t = threadIdx.x;
    const int lane = t & 63, wv = t >> 6;
    const int nrow = lane & 15, kg = lane >> 4;
    const int mt = wv >> 1, nh = wv & 1;          // wave -> (M-tile, N-half)
    const int rA = mt * 16 + nrow;

    // ---- weight fragments into registers (once per block)
    bf16x8 w1f[4][4], w2f[4][4];
#pragma unroll
    for (int nt = 0; nt < 4; ++nt) {
        int n = nh * 64 + nt * 16 + nrow;
#pragma unroll
        for (int ks = 0; ks < 4; ++ks) {
            w1f[nt][ks] = *reinterpret_cast<const bf16x8*>(&w1t[n * 128 + (ks * 4 + kg) * 8]);
            w2f[nt][ks] = *reinterpret_cast<const bf16x8*>(&w2t[n * 128 + (ks * 4 + kg) * 8]);
        }
    }
    float b1r[4], b2r[4];
#pragma unroll
    for (int nt = 0; nt < 4; ++nt) {
        int cc = nh * 64 + nt * 16 + nrow;
        b1r[nt] = b1g[cc]; b2r[nt] = b2g[cc];
    }
    const float pwl = pwg[lane & 31];

    // staging decomposition: thread -> (gene slot, d-quad, p-quad)
    const int sl = t >> 8;                 // which gene of the combo
    const int w8 = t & 255;
    const int d0 = (w8 >> 3) * 4;          // 0,4,...,124
    const int pq = w8 & 7;                 // p-quad 0..7
    const int c0 = blockIdx.x * CPB;

    float4 pf[4];
    auto loadCombo = [&](int c) {
        int gsel = locs_gene[2 * c + sl];
        const float* src = gene + (size_t)gsel * 4096 + d0 * 32 + pq * 4;
#pragma unroll
        for (int i = 0; i < 4; ++i)
            pf[i] = *reinterpret_cast<const float4*>(src + i * 32);
    };
    auto stageCombo = [&](int buf) {
        float ps[4];
#pragma unroll
        for (int q = 0; q < 4; ++q) {
            float a0 = (&pf[0].x)[q], a1 = (&pf[1].x)[q];
            float a2 = (&pf[2].x)[q], a3 = (&pf[3].x)[q];
            ps[q] = (a0 + a1) + (a2 + a3);
            uint2 v2;
            v2.x = f2bf2(a0, a1);
            v2.y = f2bf2(a2, a3);
            int r = sl * 32 + pq * 4 + q;
            *reinterpret_cast<uint2*>(
                &aBuf[buf][r * 128 + (((d0 >> 3) ^ (r & 15)) << 3) + (d0 & 7)]) = v2;
        }
        // reduce colsum partials over d within the wave (lanes pq+8k share pq)
#pragma unroll
        for (int o = 8; o <= 32; o <<= 1)
#pragma unroll
            for (int q = 0; q < 4; ++q) ps[q] += __shfl_xor(ps[q], o);
        if (lane < 8) {
#pragma unroll
            for (int q = 0; q < 4; ++q)
                pcol[buf][wv & 3][sl * 32 + pq * 4 + q] = ps[q];
        }
    };

    // ---- prologue: stage combo c0
    loadCombo(c0);
    stageCombo(0);
    __syncthreads();

    int cur = 0;
#pragma unroll 1
    for (int j = 0; j < CPB; ++j) {
        const int c = c0 + j;
        // prefetch next combo (loads stay outstanding across raw barriers)
        if (j + 1 < CPB) loadCombo(c + 1);

        // ---- wave 0: mask + softmax from staged colsum partials
        if (wv == 0) {
            float cs = pcol[cur][0][lane] + pcol[cur][1][lane]
                     + pcol[cur][2][lane] + pcol[cur][3][lane];
            float other = __shfl_down(cs, 32);
            bool m = (cs != 0.f) || (other != 0.f);
            float logit = m ? pwl : -1e9f;
            float mx = logit;
#pragma unroll
            for (int o = 16; o >= 1; o >>= 1) mx = fmaxf(mx, __shfl_xor(mx, o, 32));
            float e = __expf(logit - mx);
            float se = e;
#pragma unroll
            for (int o = 16; o >= 1; o >>= 1) se += __shfl_xor(se, o, 32);
            float w = e / se;
            if (lane < 32) { wrow[lane] = w; wrow[lane + 32] = w; }
        }

        // ---- layer 1: H1 = leaky(A @ W1 + b1)   (B from registers)
        const unsigned short* A = aBuf[cur];
        bf16x8 afr[4];
#pragma unroll
        for (int ks = 0; ks < 4; ++ks)
            afr[ks] = *reinterpret_cast<const bf16x8*>(
                &A[rA * 128 + (((ks * 4 + kg) ^ nrow) << 3)]);
        f32x4 acc1[4];
#pragma unroll
        for (int nt = 0; nt < 4; ++nt) {
            f32x4 acc = {0.f, 0.f, 0.f, 0.f};
#pragma unroll
            for (int ks = 0; ks < 4; ++ks)
                acc = __builtin_amdgcn_mfma_f32_16x16x32_bf16(afr[ks], w1f[nt][ks], acc, 0, 0, 0);
            acc1[nt] = acc;
        }
        BARRIER();   // (1) aBuf[cur] reads done; wrow written

        // ---- write H1 back into aBuf[cur] (swizzled)
        unsigned short* Aw = aBuf[cur];
#pragma unroll
        for (int nt = 0; nt < 4; ++nt) {
            int cc = nh * 64 + nt * 16 + nrow;
#pragma unroll
            for (int i = 0; i < 4; ++i) {
                int r = mt * 16 + kg * 4 + i;
                float x = acc1[nt][i] + b1r[nt];
                x = (x >= 0.f) ? x : 0.01f * x;
                Aw[swz(r, cc)] = f2bf(x);
            }
        }
        BARRIER();   // (2) H1 visible

        // ---- layer 2 + leaky + weighted pooling (B from registers)
        bf16x8 afr2[4];
#pragma unroll
        for (int ks = 0; ks < 4; ++ks)
            afr2[ks] = *reinterpret_cast<const bf16x8*>(
                &A[rA * 128 + (((ks * 4 + kg) ^ nrow) << 3)]);
        float wr[4];
#pragma unroll
        for (int i = 0; i < 4; ++i) wr[i] = wrow[mt * 16 + kg * 4 + i];
        float part[4];
#pragma unroll
        for (int nt = 0; nt < 4; ++nt) {
            f32x4 acc = {0.f, 0.f, 0.f, 0.f};
#pragma unroll
            for (int ks = 0; ks < 4; ++ks)
                acc = __builtin_amdgcn_mfma_f32_16x16x32_bf16(afr2[ks], w2f[nt][ks], acc, 0, 0, 0);
            float s = 0.f;
#pragma unroll
            for (int i = 0; i < 4; ++i) {
                float x = acc[i] + b2r[nt];
                x = (x >= 0.f) ? x : 0.01f * x;
                s = fmaf(x, wr[i], s);
            }
            part[nt] = s;
        }
        // ---- stage next combo into the other buffer (overlaps pooling)
        if (j + 1 < CPB) stageCombo(cur ^ 1);
        // ---- cross-lane then cross-wave reduction of pooled vector
#pragma unroll
        for (int nt = 0; nt < 4; ++nt) {
            float v = part[nt];
            v += __shfl_xor(v, 16);
            v += __shfl_xor(v, 32);
            part[nt] = v;
        }
        if (lane < 16) {
#pragma unroll
            for (int nt = 0; nt < 4; ++nt) pp[wv][nh * 64 + nt * 16 + lane] = part[nt];
        }
        BARRIER();   // (3) pp + staged buffer visible

        if (t < 128) {
            int base = t >> 6;
            float s = pp[base][t] + pp[base + 2][t] + pp[base + 4][t] + pp[base + 6][t];
            int seg = locs_combos[2 * c];
            poolbf[(size_t)seg * 128 + t] = f2bf(s);
        }
        if (j + 1 < CPB) cur ^= 1;
    }
}

// ---------------- K2: out = pooled @ Wout + bout  (register-only MFMA) --------
__global__ __launch_bounds__(256) void out_gemm(
    const unsigned short* __restrict__ poolbf, const unsigned short* __restrict__ woutT,
    const float* __restrict__ boutg, float* __restrict__ out)
{
    int t = threadIdx.x;
    int lane = t & 63, wv = t >> 6;
    // bijective XCD swizzle: 5024 blocks = 8 * 628; group same-bx (same WoutT
    // slice) on one XCD for L2 reuse.
    int id = blockIdx.x;
    int wk = (id & 7) * 628 + (id >> 3);
    int bx = wk >> 5, by = wk & 31;
    int nb0 = bx * 128;
    int mb0 = by * 128 + wv * 32;
    int nrow = lane & 15, kg = lane >> 4;

    bf16x8 afr[2][4];
#pragma unroll
    for (int mt = 0; mt < 2; ++mt) {
        int row = mb0 + mt * 16 + nrow;
#pragma unroll
        for (int ks = 0; ks < 4; ++ks)
            afr[mt][ks] = *reinterpret_cast<const bf16x8*>(
                &poolbf[(size_t)row * 128 + ks * 32 + kg * 8]);
    }
#pragma unroll
    for (int nt = 0; nt < 8; ++nt) {
        int n = nb0 + nt * 16 + nrow;          // < 20096 always (padded)
        f32x4 a0 = {0.f, 0.f, 0.f, 0.f}, a1 = {0.f, 0.f, 0.f, 0.f};
#pragma unroll
        for (int ks = 0; ks < 4; ++ks) {
            bf16x8 bfr = *reinterpret_cast<const bf16x8*>(
                &woutT[(size_t)n * 128 + ks * 32 + kg * 8]);
            a0 = __builtin_amdgcn_mfma_f32_16x16x32_bf16(afr[0][ks], bfr, a0, 0, 0, 0);
            a1 = __builtin_amdgcn_mfma_f32_16x16x32_bf16(afr[1][ks], bfr, a1, 0, 0, 0);
        }
        int col = nb0 + nt * 16 + nrow;
        if (col < GOUT) {
            float bias = boutg[col];
#pragma unroll
            for (int i = 0; i < 4; ++i) {
                int r0 = mb0 + kg * 4 + i;
                out[(size_t)r0 * GOUT + col] = a0[i] + bias;
                out[(size_t)(r0 + 16) * GOUT + col] = a1[i] + bias;
            }
        }
    }
}

extern "C" void kernel_launch(void* const* d_in, const int* in_sizes, int n_in,
                              void* d_out, int out_size, void* d_ws, size_t ws_size,
                              hipStream_t stream) {
    const float* gene  = (const float*)d_in[0];
    const float* W1    = (const float*)d_in[1];
    const float* b1    = (const float*)d_in[2];
    const float* W2    = (const float*)d_in[3];
    const float* b2    = (const float*)d_in[4];
    const float* pw    = (const float*)d_in[5];
    const float* Wout  = (const float*)d_in[6];
    const float* bout  = (const float*)d_in[7];
    const int* locs_gene   = (const int*)d_in[8];
    const int* locs_combos = (const int*)d_in[9];
    float* out = (float*)d_out;

    char* ws = (char*)d_ws;
    unsigned short* w1t    = (unsigned short*)(ws);
    unsigned short* w2t    = (unsigned short*)(ws + 32768);
    unsigned short* woutT  = (unsigned short*)(ws + 65536);
    unsigned short* poolbf = (unsigned short*)(ws + 65536 + (size_t)GPAD * 256);

    hipLaunchKernelGGL(prep_weights, dim3(32), dim3(256), 0, stream, W1, W2, w1t, w2t);
    hipLaunchKernelGGL(prep_wout, dim3((GPAD + 255) / 256), dim3(256), 0, stream, Wout, woutT);
    hipLaunchKernelGGL(encoder_kernel, dim3(NB / CPB), dim3(512), 0, stream,
                       gene, b1, b2, pw, locs_gene, locs_combos, w1t, w2t, poolbf);
    hipLaunchKernelGGL(out_gemm, dim3(8 * 628), dim3(256), 0, stream,
                       poolbf, woutT, bout, out);
}

// Round 4
// 258.231 us; speedup vs baseline: 1.0618x; 1.0618x over previous
//
#include <hip/hip_runtime.h>
#include <hip/hip_bf16.h>

#define GENES 20000
#define DD    128
#define PP    32
#define HH    128
#define NB    4096
#define GOUT  20000
#define GPAD  20096   // GOUT padded to multiple of 128

typedef __attribute__((ext_vector_type(8))) short bf16x8;
typedef __attribute__((ext_vector_type(4))) float f32x4;

__device__ __forceinline__ unsigned short f2bf(float f) {
    unsigned int u = __float_as_uint(f);
    unsigned int lsb = (u >> 16) & 1u;
    u += 0x7fffu + lsb;                      // RTNE
    return (unsigned short)(u >> 16);
}
__device__ __forceinline__ unsigned int f2bf2(float a, float b) {
    return (unsigned int)f2bf(a) | ((unsigned int)f2bf(b) << 16);
}

// ---------------- K0a: W1,W2 -> plain transposed bf16 (row-major [h][d]) -----
__global__ void prep_weights(const float* __restrict__ W1, const float* __restrict__ W2,
                             unsigned short* __restrict__ w1t, unsigned short* __restrict__ w2t) {
    int o = blockIdx.x * 512 + threadIdx.x;
#pragma unroll
    for (int k = 0; k < 2; ++k, o += 256) {
        int h = o >> 7, d = o & 127;
        w1t[o] = f2bf(W1[d * 128 + h]);   // W1T[h][d] = W1[d][h]
        w2t[o] = f2bf(W2[d * 128 + h]);
    }
}

// ---------------- K0b: Wout [128][20000] f32 -> WoutT [20096][128] bf16 -------
__global__ void prep_wout(const float* __restrict__ Wout, unsigned short* __restrict__ woutT) {
    int g = blockIdx.x * 256 + threadIdx.x;
    if (g >= GPAD) return;
    if (g < GOUT) {
        for (int d0 = 0; d0 < 128; d0 += 8) {
            unsigned short buf[8];
#pragma unroll
            for (int j = 0; j < 8; ++j) buf[j] = f2bf(Wout[(size_t)(d0 + j) * GOUT + g]);
            *reinterpret_cast<uint4*>(&woutT[(size_t)g * 128 + d0]) =
                *reinterpret_cast<const uint4*>(buf);
        }
    } else {
        uint4 z = {0u, 0u, 0u, 0u};
        for (int d0 = 0; d0 < 128; d0 += 8)
            *reinterpret_cast<uint4*>(&woutT[(size_t)g * 128 + d0]) = z;
    }
}

// ---------------- K1: one-shot streaming encoder (2 combos / block) ----------
// Transposed-MFMA trick: D = mfma(W^T as A, X as B) puts 4 consecutive h per
// lane -> packed b64 LDS writeback; weights read directly from global (L1-hot),
// LDS = 35 KB -> 3 blocks/CU residency; 2048 independent blocks stream.
__global__ __launch_bounds__(256, 3) void encoder_kernel(
    const float* __restrict__ gene, const float* __restrict__ b1g,
    const float* __restrict__ b2g, const float* __restrict__ pwg,
    const int* __restrict__ locs_gene, const int* __restrict__ locs_combos,
    const unsigned short* __restrict__ w1t, const unsigned short* __restrict__ w2t,
    unsigned short* __restrict__ poolbf)
{
    __shared__ __align__(16) unsigned short aT[128 * 128];   // 32 KB swizzled
    __shared__ float pcol[4][32];
    __shared__ float wrow[128];
    __shared__ float pp[4][128];

    const int t = threadIdx.x;
    const int lane = t & 63, wv = t >> 6;
    const int nrow = lane & 15, kg = lane >> 4;
    const int blk = blockIdx.x;                 // 2048 blocks, 2 combos each

    // ---- stage: wave wv loads gene slot wv (16 KB f32) into rows [wv*32,+32)
    const int pq = lane & 7, db = lane >> 3;    // p-quad 0..7, d-block 0..7
    {
        int gsel = locs_gene[blk * 4 + wv];
        const float* src = gene + (size_t)gsel * 4096 + db * 512 + pq * 4;
        float4 pf[16];
#pragma unroll
        for (int dd = 0; dd < 16; ++dd)
            pf[dd] = *reinterpret_cast<const float4*>(src + dd * 32);
        float ps[4] = {0.f, 0.f, 0.f, 0.f};
#pragma unroll
        for (int dd = 0; dd < 16; ++dd)
#pragma unroll
            for (int q = 0; q < 4; ++q) ps[q] += (&pf[dd].x)[q];
#pragma unroll
        for (int q = 0; q < 4; ++q) {
            int r = wv * 32 + pq * 4 + q;
#pragma unroll
            for (int hh = 0; hh < 2; ++hh) {
                uint4 u;
                u.x = f2bf2((&pf[hh*8+0].x)[q], (&pf[hh*8+1].x)[q]);
                u.y = f2bf2((&pf[hh*8+2].x)[q], (&pf[hh*8+3].x)[q]);
                u.z = f2bf2((&pf[hh*8+4].x)[q], (&pf[hh*8+5].x)[q]);
                u.w = f2bf2((&pf[hh*8+6].x)[q], (&pf[hh*8+7].x)[q]);
                int chunk = (db * 2 + hh) ^ (r & 15);
                *reinterpret_cast<uint4*>(&aT[r * 128 + chunk * 8]) = u;
            }
        }
        // colsum over all 128 d for (slot wv, p = pq*4+q)
#pragma unroll
        for (int o = 8; o <= 32; o <<= 1)
#pragma unroll
            for (int q = 0; q < 4; ++q) ps[q] += __shfl_xor(ps[q], o);
        if (db == 0) {
#pragma unroll
            for (int q = 0; q < 4; ++q) pcol[wv][pq * 4 + q] = ps[q];
        }
    }
    __syncthreads();   // (1) pcol + staged tiles visible

    // ---- mask + softmax over pathways (waves 0,1 -> combo wv)
    if (wv < 2 && lane < 32) {
        float cs0 = pcol[wv * 2][lane], cs1 = pcol[wv * 2 + 1][lane];
        bool m = (cs0 != 0.f) || (cs1 != 0.f);
        float logit = m ? pwg[lane] : -1e9f;
        float mx = logit;
#pragma unroll
        for (int o = 16; o >= 1; o >>= 1) mx = fmaxf(mx, __shfl_xor(mx, o, 32));
        float e = __expf(logit - mx);
        float se = e;
#pragma unroll
        for (int o = 16; o >= 1; o >>= 1) se += __shfl_xor(se, o, 32);
        float w = e / se;
        wrow[wv * 64 + lane] = w;
        wrow[wv * 64 + 32 + lane] = w;
    }

    // ---- layer 1: A = W1T rows (global), B = X rows (own aT strip)
    bf16x8 bfr[2][4];
#pragma unroll
    for (int nt = 0; nt < 2; ++nt) {
        int s = wv * 32 + nt * 16 + nrow;
#pragma unroll
        for (int ks = 0; ks < 4; ++ks) {
            int chunk = (ks * 4 + kg) ^ (s & 15);
            bfr[nt][ks] = *reinterpret_cast<const bf16x8*>(&aT[s * 128 + chunk * 8]);
        }
    }
    f32x4 acc[8][2];
#pragma unroll
    for (int mt = 0; mt < 8; ++mt) {
        f32x4 z = {0.f, 0.f, 0.f, 0.f};
        acc[mt][0] = z; acc[mt][1] = z;
        int hrow = mt * 16 + nrow;
#pragma unroll
        for (int ks = 0; ks < 4; ++ks) {
            bf16x8 af = *reinterpret_cast<const bf16x8*>(&w1t[hrow * 128 + ks * 32 + kg * 8]);
            acc[mt][0] = __builtin_amdgcn_mfma_f32_16x16x32_bf16(af, bfr[0][ks], acc[mt][0], 0, 0, 0);
            acc[mt][1] = __builtin_amdgcn_mfma_f32_16x16x32_bf16(af, bfr[1][ks], acc[mt][1], 0, 0, 0);
        }
    }
    // epilogue: bias + leaky, packed b64 writeback of 4 consecutive h per lane
#pragma unroll
    for (int mt = 0; mt < 8; ++mt) {
        int h0 = mt * 16 + kg * 4;
        float4 bq = *reinterpret_cast<const float4*>(&b1g[h0]);
#pragma unroll
        for (int nt = 0; nt < 2; ++nt) {
            int s = wv * 32 + nt * 16 + nrow;
            float x0 = acc[mt][nt][0] + bq.x; x0 = (x0 >= 0.f) ? x0 : 0.01f * x0;
            float x1 = acc[mt][nt][1] + bq.y; x1 = (x1 >= 0.f) ? x1 : 0.01f * x1;
            float x2 = acc[mt][nt][2] + bq.z; x2 = (x2 >= 0.f) ? x2 : 0.01f * x2;
            float x3 = acc[mt][nt][3] + bq.w; x3 = (x3 >= 0.f) ? x3 : 0.01f * x3;
            uint2 v2 = {f2bf2(x0, x1), f2bf2(x2, x3)};
            int chunk = (mt * 2 + (kg >> 1)) ^ (s & 15);
            *reinterpret_cast<uint2*>(&aT[s * 128 + chunk * 8 + (kg & 1) * 4]) = v2;
        }
    }
    __syncthreads();   // (2) H1 + wrow visible

    // ---- layer 2: A = W2T rows (global), B = H1 rows (own aT strip)
    bf16x8 bfr2[2][4];
#pragma unroll
    for (int nt = 0; nt < 2; ++nt) {
        int s = wv * 32 + nt * 16 + nrow;
#pragma unroll
        for (int ks = 0; ks < 4; ++ks) {
            int chunk = (ks * 4 + kg) ^ (s & 15);
            bfr2[nt][ks] = *reinterpret_cast<const bf16x8*>(&aT[s * 128 + chunk * 8]);
        }
    }
    float wr0 = wrow[wv * 32 + nrow];
    float wr1 = wrow[wv * 32 + 16 + nrow];
    float pool[8][4];
#pragma unroll
    for (int mt = 0; mt < 8; ++mt)
#pragma unroll
        for (int i = 0; i < 4; ++i) pool[mt][i] = 0.f;
#pragma unroll
    for (int mt = 0; mt < 8; ++mt) {
        f32x4 z = {0.f, 0.f, 0.f, 0.f};
        f32x4 a0 = z, a1 = z;
        int hrow = mt * 16 + nrow;
#pragma unroll
        for (int ks = 0; ks < 4; ++ks) {
            bf16x8 af = *reinterpret_cast<const bf16x8*>(&w2t[hrow * 128 + ks * 32 + kg * 8]);
            a0 = __builtin_amdgcn_mfma_f32_16x16x32_bf16(af, bfr2[0][ks], a0, 0, 0, 0);
            a1 = __builtin_amdgcn_mfma_f32_16x16x32_bf16(af, bfr2[1][ks], a1, 0, 0, 0);
        }
        int h0 = mt * 16 + kg * 4;
        float4 bq = *reinterpret_cast<const float4*>(&b2g[h0]);
#pragma unroll
        for (int i = 0; i < 4; ++i) {
            float x0 = a0[i] + (&bq.x)[i]; x0 = (x0 >= 0.f) ? x0 : 0.01f * x0;
            float x1 = a1[i] + (&bq.x)[i]; x1 = (x1 >= 0.f) ? x1 : 0.01f * x1;
            pool[mt][i] = fmaf(x0, wr0, pool[mt][i]);
            pool[mt][i] = fmaf(x1, wr1, pool[mt][i]);
        }
    }
    // reduce pooled partials over the 16 s-lanes (nrow bits)
#pragma unroll
    for (int mt = 0; mt < 8; ++mt)
#pragma unroll
        for (int i = 0; i < 4; ++i) {
            float v = pool[mt][i];
            v += __shfl_xor(v, 1);
            v += __shfl_xor(v, 2);
            v += __shfl_xor(v, 4);
            v += __shfl_xor(v, 8);
            pool[mt][i] = v;
        }
    if (nrow == 0) {
#pragma unroll
        for (int mt = 0; mt < 8; ++mt)
#pragma unroll
            for (int i = 0; i < 4; ++i)
                pp[wv][mt * 16 + kg * 4 + i] = pool[mt][i];
    }
    __syncthreads();   // (3) pp complete

    {
        int cb = t >> 7, h = t & 127;
        float v = pp[cb * 2][h] + pp[cb * 2 + 1][h];
        int seg = locs_combos[2 * (blk * 2 + cb)];
        poolbf[(size_t)seg * 128 + h] = f2bf(v);
    }
}

// ---------------- K2: out = pooled @ Wout + bout  (register-only MFMA) --------
__global__ __launch_bounds__(256) void out_gemm(
    const unsigned short* __restrict__ poolbf, const unsigned short* __restrict__ woutT,
    const float* __restrict__ boutg, float* __restrict__ out)
{
    int t = threadIdx.x;
    int lane = t & 63, wv = t >> 6;
    int nb0 = blockIdx.x * 128;
    int mb0 = blockIdx.y * 128 + wv * 32;
    int nrow = lane & 15, kg = lane >> 4;

    bf16x8 afr[2][4];
#pragma unroll
    for (int mt = 0; mt < 2; ++mt) {
        int row = mb0 + mt * 16 + nrow;
#pragma unroll
        for (int ks = 0; ks < 4; ++ks)
            afr[mt][ks] = *reinterpret_cast<const bf16x8*>(
                &poolbf[(size_t)row * 128 + ks * 32 + kg * 8]);
    }
#pragma unroll
    for (int nt = 0; nt < 8; ++nt) {
        int n = nb0 + nt * 16 + nrow;          // < 20096 always (padded)
        f32x4 a0 = {0.f, 0.f, 0.f, 0.f}, a1 = {0.f, 0.f, 0.f, 0.f};
#pragma unroll
        for (int ks = 0; ks < 4; ++ks) {
            bf16x8 bfr = *reinterpret_cast<const bf16x8*>(
                &woutT[(size_t)n * 128 + ks * 32 + kg * 8]);
            a0 = __builtin_amdgcn_mfma_f32_16x16x32_bf16(afr[0][ks], bfr, a0, 0, 0, 0);
            a1 = __builtin_amdgcn_mfma_f32_16x16x32_bf16(afr[1][ks], bfr, a1, 0, 0, 0);
        }
        int col = nb0 + nt * 16 + nrow;
        if (col < GOUT) {
            float bias = boutg[col];
#pragma unroll
            for (int i = 0; i < 4; ++i) {
                int r0 = mb0 + kg * 4 + i;
                out[(size_t)r0 * GOUT + col] = a0[i] + bias;
                out[(size_t)(r0 + 16) * GOUT + col] = a1[i] + bias;
            }
        }
    }
}

extern "C" void kernel_launch(void* const* d_in, const int* in_sizes, int n_in,
                              void* d_out, int out_size, void* d_ws, size_t ws_size,
                              hipStream_t stream) {
    const float* gene  = (const float*)d_in[0];
    const float* W1    = (const float*)d_in[1];
    const float* b1    = (const float*)d_in[2];
    const float* W2    = (const float*)d_in[3];
    const float* b2    = (const float*)d_in[4];
    const float* pw    = (const float*)d_in[5];
    const float* Wout  = (const float*)d_in[6];
    const float* bout  = (const float*)d_in[7];
    const int* locs_gene   = (const int*)d_in[8];
    const int* locs_combos = (const int*)d_in[9];
    float* out = (float*)d_out;

    char* ws = (char*)d_ws;
    unsigned short* w1t    = (unsigned short*)(ws);
    unsigned short* w2t    = (unsigned short*)(ws + 32768);
    unsigned short* woutT  = (unsigned short*)(ws + 65536);
    unsigned short* poolbf = (unsigned short*)(ws + 65536 + (size_t)GPAD * 256);

    hipLaunchKernelGGL(prep_weights, dim3(32), dim3(256), 0, stream, W1, W2, w1t, w2t);
    hipLaunchKernelGGL(prep_wout, dim3((GPAD + 255) / 256), dim3(256), 0, stream, Wout, woutT);
    hipLaunchKernelGGL(encoder_kernel, dim3(NB / 2), dim3(256), 0, stream,
                       gene, b1, b2, pw, locs_gene, locs_combos, w1t, w2t, poolbf);
    hipLaunchKernelGGL(out_gemm, dim3(GPAD / 128, 32), dim3(256), 0, stream,
                       poolbf, woutT, bout, out);
}